// Round 18
// baseline (60.502 us; speedup 1.0000x reference)
//
#include <hip/hip_runtime.h>

#define NB 16
#define NM 32
#define NA 8400
#define NCC 80
#define NREG 64
#define A0 6400
#define A1 1600
#define A2 400
#define CAP 768

#define TILES_PER_B 34          // 25 (lvl0) + 7 (lvl1) + 2 (lvl2)
#define DEC_BLKS (NB * TILES_PER_B)   // 544
#define ASN_BLKS (NB * NM)            // 512
#define BCE1_BLKS 1024
#define BCE2_BLKS 1024
#define G1 (DEC_BLKS + BCE1_BLKS)
#define G2 (ASN_BLKS + BCE2_BLKS)
#define PL_GRID 525             // 525*256 == NB*NA exactly

// ---------- device helpers ----------

__device__ __forceinline__ void anch(int a, float& ax, float& ay, float& s, int& lvl, int& p) {
  if (a < A0)            { lvl = 0; p = a;          s = 8.f;  ax = (float)(p % 80); ay = (float)(p / 80); }
  else if (a < A0 + A1)  { lvl = 1; p = a - A0;     s = 16.f; ax = (float)(p % 40); ay = (float)(p / 40); }
  else                   { lvl = 2; p = a - A0 - A1; s = 32.f; ax = (float)(p % 20); ay = (float)(p / 20); }
}

__device__ __forceinline__ float cls_at(const float* c0, const float* c1, const float* c2,
                                        int b, int ch, int a) {
  if (a < A0)           return c0[((size_t)(b * NCC + ch)) * A0 + a];
  if (a < A0 + A1)      return c1[((size_t)(b * NCC + ch)) * A1 + (a - A0)];
  return c2[((size_t)(b * NCC + ch)) * A2 + (a - A0 - A1)];
}

__device__ __forceinline__ float reg_at(const float* r0, const float* r1, const float* r2,
                                        int b, int ch, int lvl, int p) {
  if (lvl == 0) return r0[((size_t)(b * NREG + ch)) * A0 + p];
  if (lvl == 1) return r1[((size_t)(b * NREG + ch)) * A1 + p];
  return r2[((size_t)(b * NREG + ch)) * A2 + p];
}

__device__ __forceinline__ void gtbox(const float* boxes, int b, int m,
                                      float& x1, float& y1, float& x2, float& y2, bool& valid) {
  const float* q = boxes + ((size_t)(b * NM + m)) * 4;
  float cx = q[0], cy = q[1], w = q[2], h = q[3];
  x1 = (cx - w * 0.5f) * 640.f; y1 = (cy - h * 0.5f) * 640.f;
  x2 = (cx + w * 0.5f) * 640.f; y2 = (cy + h * 0.5f) * 640.f;
  valid = (x1 + y1 + x2 + y2) > 0.f;
}

__device__ __forceinline__ float ciou_f(float b1x1, float b1y1, float b1x2, float b1y2,
                                        float b2x1, float b2y1, float b2x2, float b2y2) {
  const float eps = 1e-7f;
  float w1 = b1x2 - b1x1, h1 = b1y2 - b1y1;
  float w2 = b2x2 - b2x1, h2 = b2y2 - b2y1;
  float iw = fmaxf(fminf(b1x2, b2x2) - fmaxf(b1x1, b2x1), 0.f);
  float ih = fmaxf(fminf(b1y2, b2y2) - fmaxf(b1y1, b2y1), 0.f);
  float inter = iw * ih;
  float uni = w1 * h1 + w2 * h2 - inter + eps;
  float iou = inter / uni;
  float cw = fmaxf(b1x2, b2x2) - fminf(b1x1, b2x1);
  float ch = fmaxf(b1y2, b2y2) - fminf(b1y1, b2y1);
  float c2 = cw * cw + ch * ch + eps;
  float dx = b2x1 + b2x2 - b1x1 - b1x2;
  float dy = b2y1 + b2y2 - b1y1 - b1y2;
  float rho2 = (dx * dx + dy * dy) * 0.25f;
  float at = atanf(w2 / (h2 + eps)) - atanf(w1 / (h1 + eps));
  float v = 0.4052847345693511f * at * at;   // 4/pi^2
  float alpha = v / (v - iou + (1.0f + eps));
  return iou - (rho2 / c2 + v * alpha);
}

__device__ __forceinline__ float align_of(float sc, float o) {
  float o2 = o * o, o4 = o2 * o2;
  return sqrtf(sc) * (o2 * o4);  // sc^0.5 * o^6
}

__device__ __forceinline__ float softplus_fast(float x) {
  float e = __expf(-fabsf(x));
  return fmaxf(x, 0.f) + __logf(1.f + e);
}

// BCE softplus over a float4 index range [lo, hi) with grid-stride of nblk blocks
__device__ __forceinline__ void bce_range(const float* c0, const float* c1, const float* c2,
                                          int blk, int nblk, size_t lo, size_t hi,
                                          double* slot, double* sred, int tid) {
  const size_t N0 = (size_t)NB * NCC * A0 / 4;
  const size_t N1 = (size_t)NB * NCC * A1 / 4;
  const float4* f0 = (const float4*)c0;
  const float4* f1 = (const float4*)c1;
  const float4* f2 = (const float4*)c2;
  float s0 = 0.f, s1 = 0.f;
  for (size_t i = lo + (size_t)blk * 256 + tid; i < hi; i += (size_t)nblk * 256) {
    float4 v;
    if (i < N0) v = f0[i];
    else if (i < N0 + N1) v = f1[i - N0];
    else v = f2[i - N0 - N1];
    s0 += softplus_fast(v.x) + softplus_fast(v.z);
    s1 += softplus_fast(v.y) + softplus_fast(v.w);
  }
  sred[tid] = (double)(s0 + s1);
  __syncthreads();
  for (int off = 128; off; off >>= 1) {
    if (tid < off) sred[tid] += sred[tid + off];
    __syncthreads();
  }
  if (tid == 0) *slot = sred[0];
}

#define NT4 ((size_t)NB * NCC * NA / 4)     // 2688000
#define NT4_HALF (NT4 / 2)

// ---------- kernel 1: LDS-transpose decode (float4 staging) ∥ zero + BCE half 1 ----------

__global__ __launch_bounds__(256) void k_d1(
    const float* r0, const float* r1, const float* r2,
    const float* c0, const float* c1, const float* c2,
    float4* bb4, float4* mls4, int* fgcnt, int* msum,
    unsigned* pos_am, unsigned* pos_ov, double* gt_acc, int* done_ctr,
    double* bce_part) {
  __shared__ __align__(16) float lds[32 * 256];
  const int tid = threadIdx.x;

  if (blockIdx.x >= DEC_BLKS) {
    // zero scratch + BCE first half
    const int zb = blockIdx.x - DEC_BLKS;
    const int gz = zb * 256 + tid;
    if (gz < NB * NA) { fgcnt[gz] = 0; msum[gz] = 0; }
    if (gz < NB * NM) { pos_am[gz] = 0u; pos_ov[gz] = 0u; }
    if (gz < NB * NM * 4) gt_acc[gz] = 0.0;
    if (gz == 0) *done_ctr = 0;
    bce_range(c0, c1, c2, zb, BCE1_BLKS, 0, NT4_HALF,
              &bce_part[zb], (double*)lds, tid);
    return;
  }

  const int d = blockIdx.x;
  const int b = d / TILES_PER_B, u = d % TILES_PER_B;
  int lvl, tile;
  if (u < 25)      { lvl = 0; tile = u; }
  else if (u < 32) { lvl = 1; tile = u - 25; }
  else             { lvl = 2; tile = u - 32; }
  const int HW   = (lvl == 0) ? A0 : (lvl == 1 ? A1 : A2);
  const int W    = (lvl == 0) ? 80 : (lvl == 1 ? 40 : 20);
  const int loff = (lvl == 0) ? 0  : (lvl == 1 ? A0 : A0 + A1);
  const float* rg = (lvl == 0) ? r0 : (lvl == 1 ? r1 : r2);
  const int base_p = tile * 256;
  const int valid  = min(256, HW - base_p);
  const float* src = rg + (size_t)b * NREG * HW + base_p;

  const int g4 = tid >> 6;   // row-within-group-of-4
  const int l4 = tid & 63;   // float4 column index

  float dist[4], mlv[4];
#pragma unroll
  for (int ph = 0; ph < 2; ++ph) {
    if (l4 * 4 < valid) {
#pragma unroll
      for (int c4 = 0; c4 < 8; ++c4) {
        int ch = c4 * 4 + g4;
        float4 v = *(const float4*)(src + (size_t)(ph * 32 + ch) * HW + l4 * 4);
        *(float4*)&lds[ch * 256 + l4 * 4] = v;
      }
    }
    __syncthreads();
    if (tid < valid) {
#pragma unroll
      for (int sh = 0; sh < 2; ++sh) {
        const float* col = &lds[(sh * 16) * 256 + tid];
        float mx = col[0];
#pragma unroll
        for (int r = 1; r < 16; ++r) mx = fmaxf(mx, col[r * 256]);
        float se = 0.f, ws = 0.f;
#pragma unroll
        for (int r = 0; r < 16; ++r) {
          float e = __expf(col[r * 256] - mx);
          se += e; ws += e * (float)r;
        }
        dist[ph * 2 + sh] = ws / se;
        mlv[ph * 2 + sh]  = mx + __logf(se);
      }
    }
    __syncthreads();
  }
  if (tid < valid) {
    int p = base_p + tid;
    float ax = (float)(p % W), ay = (float)(p / W);
    int t = b * NA + loff + p;
    bb4[t]  = make_float4(ax - dist[0], ay - dist[1], ax + dist[2], ay + dist[3]);
    mls4[t] = make_float4(mlv[0], mlv[1], mlv[2], mlv[3]);
  }
}

// ---------- kernel 2: assign (blocks < ASN_BLKS) ∥ BCE half 2 ----------

__global__ __launch_bounds__(256) void k_d2(
    const float* boxes, const int* labels, const float4* bb,
    const float* c0, const float* c1, const float* c2,
    int* fgcnt, int* msum, double* bce_part) {
  __shared__ float sv[CAP];
  __shared__ int   si[CAP];
  __shared__ int   s_n;
  __shared__ double sred[256];
  const int tid = threadIdx.x;

  if (blockIdx.x >= ASN_BLKS) {
    const int zb = blockIdx.x - ASN_BLKS;
    bce_range(c0, c1, c2, zb, BCE2_BLKS, NT4_HALF, NT4,
              &bce_part[BCE1_BLKS + zb], sred, tid);
    return;
  }

  const int bm = blockIdx.x;
  const int b = bm / NM, m = bm % NM;
  const int lane = tid & 63;

  float gx1, gy1, gx2, gy2; bool valid;
  gtbox(boxes, b, m, gx1, gy1, gx2, gy2, valid);
  if (!valid) return;   // uniform per block
  int lbl = labels[bm]; if (lbl < 0) lbl = 0; if (lbl >= NCC) lbl = NCC - 1;
  if (tid == 0) s_n = 0;
  __syncthreads();

  const int   Ws[3]   = {80, 40, 20};
  const float ss[3]   = {8.f, 16.f, 32.f};
  const int   loff[3] = {0, A0, A0 + A1};
  int rx0[3], ry0[3], rw[3], bc[3];
  int total = 0;
  for (int l = 0; l < 3; ++l) {
    float s = ss[l]; int W = Ws[l];
    int ax0 = (int)floorf((gx1 + 1e-9f) / s);
    int ax1 = (int)ceilf((gx2 - 1e-9f) / s);
    int ay0 = (int)floorf((gy1 + 1e-9f) / s);
    int ay1 = (int)ceilf((gy2 - 1e-9f) / s);
    ax0 = max(ax0, 0); ay0 = max(ay0, 0);
    ax1 = min(ax1, W - 1); ay1 = min(ay1, W - 1);
    rx0[l] = ax0; ry0[l] = ay0;
    rw[l] = max(0, ax1 - ax0 + 1);
    int rhl = max(0, ay1 - ay0 + 1);
    bc[l] = total;
    total += rw[l] * rhl;
  }
  int iters = (total + 255) >> 8;
  for (int it = 0; it < iters; ++it) {
    int idx = it * 256 + tid;
    bool pred = false; float am = 0.f; int a = 0;
    if (idx < total) {
      int l = (idx >= bc[2]) ? 2 : ((idx >= bc[1]) ? 1 : 0);
      int r = idx - bc[l];
      int iy = r / rw[l], ix = r - iy * rw[l];
      int axg = rx0[l] + ix, ayg = ry0[l] + iy;
      a = loff[l] + ayg * Ws[l] + axg;
      float s = ss[l];
      float axp = (float)axg * s, ayp = (float)ayg * s;
      float mn = fminf(fminf(axp - gx1, ayp - gy1), fminf(gx2 - axp, gy2 - ayp));
      if (mn > 1e-9f) {
        pred = true;
        float4 pb = bb[(size_t)b * NA + a];
        float c = ciou_f(gx1, gy1, gx2, gy2, pb.x * s, pb.y * s, pb.z * s, pb.w * s);
        float o = fmaxf(c, 0.f);
        float x = cls_at(c0, c1, c2, b, lbl, a);
        float sc = 1.f / (1.f + expf(-x));
        am = align_of(sc, o);
      }
    }
    unsigned long long mask = __ballot(pred);
    if (mask) {
      int nact = __popcll(mask);
      int leader = __ffsll(mask) - 1;
      int basec = 0;
      if (lane == leader) basec = atomicAdd(&s_n, nact);
      basec = __shfl(basec, leader);
      if (pred) {
        int off = basec + __popcll(mask & ((1ull << lane) - 1ull));
        if (off < CAP) { sv[off] = am; si[off] = a; }
      }
    }
  }
  __syncthreads();
  int n = s_n; if (n > CAP) n = CAP;
  if (n == 0) return;
  if (tid >= 64) return;           // selection: wave 0 only, wave-synchronous

  float v[12]; int ix[12];
#pragma unroll
  for (int k = 0; k < 12; ++k) {
    int j = k * 64 + tid;
    bool in = (j < n);
    v[k]  = in ? sv[j] : -2.f;
    ix[k] = in ? si[j] : (1 << 30);
  }
  int cnt = 0;
#pragma unroll
  for (int k = 0; k < 12; ++k) cnt += (v[k] > 0.f) ? 1 : 0;
  for (int o = 32; o; o >>= 1) cnt += __shfl_xor(cnt, o);
  int npos = cnt;

  if (npos > 10) {
    for (int p = 0; p < 10; ++p) {
      float bv = -1.f; int bi = 1 << 30;
#pragma unroll
      for (int k = 0; k < 12; ++k) {
        if (v[k] > bv || (v[k] == bv && ix[k] < bi)) { bv = v[k]; bi = ix[k]; }
      }
      for (int o = 32; o; o >>= 1) {
        float wv = __shfl_xor(bv, o); int wi = __shfl_xor(bi, o);
        if (wv > bv || (wv == bv && wi < bi)) { bv = wv; bi = wi; }
      }
#pragma unroll
      for (int k = 0; k < 12; ++k) if (ix[k] == bi) v[k] = -1.f;
      if (tid == 0) {
        atomicAdd(&fgcnt[(size_t)b * NA + bi], 1);   // fire-and-forget
        atomicAdd(&msum[(size_t)b * NA + bi], m);
      }
    }
  } else {
#pragma unroll
    for (int k = 0; k < 12; ++k) {
      if (v[k] > 0.f) {
        atomicAdd(&fgcnt[(size_t)b * NA + ix[k]], 1);
        atomicAdd(&msum[(size_t)b * NA + ix[k]], m);
      }
    }
    // zero-tie fill (anchor index < 10 — rare corner); sv/si in LDS unmodified
    int need = 10 - npos;
    for (int j = tid; j < n; j += 64) {
      if (sv[j] == 0.f) {
        int i = si[j];
        if (i < 10) {
          int pb = 0;
          for (int q = 0; q < n; ++q) pb += (sv[q] > 0.f && si[q] < i) ? 1 : 0;
          if (i - pb < need) {
            atomicAdd(&fgcnt[(size_t)b * NA + i], 1);
            atomicAdd(&msum[(size_t)b * NA + i], m);
          }
        }
      }
    }
  }
}

// ---------- kernel 3: resolve + per-gt buckets + last-block final compose ----------

__global__ __launch_bounds__(256) void k_rpf(
    const float* boxes, const int* labels,
    const float4* bb, const float4* mls,
    const float* c0, const float* c1, const float* c2,
    const float* r0, const float* r1, const float* r2,
    const int* fgcnt, const int* msum,
    unsigned* pos_am, unsigned* pos_ov, double* gt_acc,
    int* done_ctr, const double* bce_part, float* out) {
  const int tid = threadIdx.x;
  const int t = blockIdx.x * 256 + tid;   // grid covers NB*NA exactly
  int fg = fgcnt[t];
  if (fg > 0) {
    int b = t / NA, a = t % NA;
    float ax, ay, s; int lvl, p;
    anch(a, ax, ay, s, lvl, p);
    float axp = ax * s, ayp = ay * s;
    float4 pb = bb[t];
    float px1 = pb.x * s, py1 = pb.y * s, px2 = pb.z * s, py2 = pb.w * s;
    int asn; float o;
    if (fg == 1) {
      asn = msum[t];
      float gx1, gy1, gx2, gy2; bool valid;
      gtbox(boxes, b, asn, gx1, gy1, gx2, gy2, valid);
      o = fmaxf(ciou_f(gx1, gy1, gx2, gy2, px1, py1, px2, py2), 0.f);
    } else {
      float bv = -1e30f; int bi = 0;
      for (int m = 0; m < NM; ++m) {
        float gx1, gy1, gx2, gy2; bool valid;
        gtbox(boxes, b, m, gx1, gy1, gx2, gy2, valid);
        float om = 0.f;
        if (valid) {
          float mn = fminf(fminf(axp - gx1, ayp - gy1), fminf(gx2 - axp, gy2 - ayp));
          if (mn > 1e-9f)
            om = fmaxf(ciou_f(gx1, gy1, gx2, gy2, px1, py1, px2, py2), 0.f);
        }
        if (om > bv) { bv = om; bi = m; }
      }
      asn = bi; o = bv;
    }
    if (o > 0.f) {
      int g = b * NM + asn;
      int lbl = labels[g]; if (lbl < 0) lbl = 0; if (lbl >= NCC) lbl = NCC - 1;
      float x = cls_at(c0, c1, c2, b, lbl, a);
      float sc = 1.f / (1.f + expf(-x));
      float am = align_of(sc, o);
      atomicMax(&pos_am[g], __float_as_uint(am));
      atomicMax(&pos_ov[g], __float_as_uint(o));
      if (am > 0.f) {
        float gx1, gy1, gx2, gy2; bool valid;
        gtbox(boxes, b, asn, gx1, gy1, gx2, gy2, valid);
        float inv_s = 1.f / s;
        float tx1 = gx1 * inv_s, ty1 = gy1 * inv_s, tx2 = gx2 * inv_s, ty2 = gy2 * inv_s;
        float iou = ciou_f(pb.x, pb.y, pb.z, pb.w, tx1, ty1, tx2, ty2);
        float4 ml = mls[t];
        float tgt[4] = { ax - tx1, ay - ty1, tx2 - ax, ty2 - ay };
        float mlv[4] = { ml.x, ml.y, ml.z, ml.w };
        float dfl = 0.f;
        for (int sd = 0; sd < 4; ++sd) {
          float tv = fminf(fmaxf(tgt[sd], 0.f), 14.99f);
          float tlf = floorf(tv);
          int tl = (int)tlf;
          float wl = (tlf + 1.f) - tv;
          float xtl = reg_at(r0, r1, r2, b, sd * 16 + tl,     lvl, p);
          float xtr = reg_at(r0, r1, r2, b, sd * 16 + tl + 1, lvl, p);
          dfl += -((xtl - mlv[sd]) * wl + (xtr - mlv[sd]) * (1.f - wl));
        }
        dfl *= 0.25f;
        atomicAdd(&gt_acc[g * 4 + 0], (double)am);
        atomicAdd(&gt_acc[g * 4 + 1], (double)(am * x));
        atomicAdd(&gt_acc[g * 4 + 2], (double)(am * (1.f - iou)));
        atomicAdd(&gt_acc[g * 4 + 3], (double)(am * dfl));
      }
    }
  }

  // ---- last-block-done epilogue (atomics are per-address coherent; no fence) ----
  __shared__ int s_last;
  __syncthreads();
  if (tid == 0) {
    int old = atomicAdd(done_ctr, 1);
    s_last = (old == (int)gridDim.x - 1) ? 1 : 0;
  }
  __syncthreads();
  if (!s_last) return;

  double tss = 0.0, sx = 0.0, siou = 0.0, sdfl = 0.0, bce = 0.0;
  for (int g = tid; g < NB * NM; g += 256) {
    float pam = __uint_as_float(atomicAdd(&pos_am[g], 0u));
    float pov = __uint_as_float(atomicAdd(&pos_ov[g], 0u));
    double sc = (double)pov / ((double)pam + 1e-9);
    tss  += atomicAdd(&gt_acc[g * 4 + 0], 0.0) * sc;
    sx   += atomicAdd(&gt_acc[g * 4 + 1], 0.0) * sc;
    siou += atomicAdd(&gt_acc[g * 4 + 2], 0.0) * sc;
    sdfl += atomicAdd(&gt_acc[g * 4 + 3], 0.0) * sc;
  }
  for (int i = tid; i < BCE1_BLKS + BCE2_BLKS; i += 256) bce += bce_part[i];
  __shared__ double sred[256];
  double vals[5] = { tss, sx, siou, sdfl, bce };
  double tot[5];
  for (int q = 0; q < 5; ++q) {
    sred[tid] = vals[q];
    __syncthreads();
    for (int off = 128; off; off >>= 1) {
      if (tid < off) sred[tid] += sred[tid + off];
      __syncthreads();
    }
    tot[q] = sred[0];
    __syncthreads();
  }
  if (tid == 0) {
    double t5 = tot[0]; if (t5 < 1.0) t5 = 1.0;
    double l0 = 0.5 * (tot[4] - tot[1]) / t5;
    double l1 = 7.5 * tot[2] / t5;
    double l2 = 1.5 * tot[3] / t5;
    out[0] = (float)(l0 + l1 + l2);
    out[1] = (float)l0;
    out[2] = (float)l1;
    out[3] = (float)l2;
  }
}

// ---------- launch ----------

extern "C" void kernel_launch(void* const* d_in, const int* in_sizes, int n_in,
                              void* d_out, int out_size, void* d_ws, size_t ws_size,
                              hipStream_t stream) {
  (void)in_sizes; (void)n_in; (void)out_size; (void)ws_size;
  const float* cls0  = (const float*)d_in[0];
  const float* cls1  = (const float*)d_in[1];
  const float* cls2  = (const float*)d_in[2];
  const float* reg0  = (const float*)d_in[3];
  const float* reg1  = (const float*)d_in[4];
  const float* reg2  = (const float*)d_in[5];
  const float* boxes = (const float*)d_in[6];
  const int*   labels = (const int*)d_in[7];
  float* out = (float*)d_out;

  const size_t BA = (size_t)NB * NA;  // 134400
  const int    BM = NB * NM;          // 512

  char* wsb = (char*)d_ws;
  double*   bce_part = (double*)wsb;                        // BCE1+BCE2
  double*   gt_acc   = bce_part + BCE1_BLKS + BCE2_BLKS;    // BM*4   (zeroed in k_d1)
  unsigned* pos_am   = (unsigned*)(gt_acc + (size_t)BM * 4);// BM     (zeroed)
  unsigned* pos_ov   = pos_am + BM;                         // BM     (zeroed)
  int*      done_ctr = (int*)(pos_ov + BM);                 // 1 (+pad, zeroed)
  int*      fgcnt    = done_ctr + 4;                        // BA     (zeroed)
  int*      msum     = fgcnt + BA;                          // BA     (zeroed)
  float*    bbp      = (float*)(msum + BA);                 // BA*4
  float*    mlsp     = bbp + BA * 4;                        // BA*4

  float4* bb  = (float4*)bbp;
  float4* mls = (float4*)mlsp;

  k_d1<<<G1, 256, 0, stream>>>(reg0, reg1, reg2, cls0, cls1, cls2, bb, mls,
                               fgcnt, msum, pos_am, pos_ov, gt_acc, done_ctr, bce_part);
  k_d2<<<G2, 256, 0, stream>>>(boxes, labels, (const float4*)bb,
                               cls0, cls1, cls2, fgcnt, msum, bce_part);
  k_rpf<<<PL_GRID, 256, 0, stream>>>(boxes, labels, (const float4*)bb, (const float4*)mls,
                                     cls0, cls1, cls2, reg0, reg1, reg2,
                                     fgcnt, msum, pos_am, pos_ov, gt_acc,
                                     done_ctr, bce_part, out);
}

// Round 19
// 58.354 us; speedup vs baseline: 1.0368x; 1.0368x over previous
//
#include <hip/hip_runtime.h>

#define NB 16
#define NM 32
#define NA 8400
#define NCC 80
#define NREG 64
#define A0 6400
#define A1 1600
#define A2 400
#define CAP 768

#define TILES_PER_B 34          // 25 (lvl0) + 7 (lvl1) + 2 (lvl2)
#define DEC_BLKS (NB * TILES_PER_B)   // 544 (544*256 = 139264 >= NB*NA)
#define ASN_BLKS (NB * NM)            // 512
#define BCE_BLKS 2048
#define MID_GRID (ASN_BLKS + BCE_BLKS)
#define PL_GRID 525             // 525*256 == NB*NA exactly

// ---------- device helpers ----------

__device__ __forceinline__ void anch(int a, float& ax, float& ay, float& s, int& lvl, int& p) {
  if (a < A0)            { lvl = 0; p = a;          s = 8.f;  ax = (float)(p % 80); ay = (float)(p / 80); }
  else if (a < A0 + A1)  { lvl = 1; p = a - A0;     s = 16.f; ax = (float)(p % 40); ay = (float)(p / 40); }
  else                   { lvl = 2; p = a - A0 - A1; s = 32.f; ax = (float)(p % 20); ay = (float)(p / 20); }
}

__device__ __forceinline__ float cls_at(const float* c0, const float* c1, const float* c2,
                                        int b, int ch, int a) {
  if (a < A0)           return c0[((size_t)(b * NCC + ch)) * A0 + a];
  if (a < A0 + A1)      return c1[((size_t)(b * NCC + ch)) * A1 + (a - A0)];
  return c2[((size_t)(b * NCC + ch)) * A2 + (a - A0 - A1)];
}

__device__ __forceinline__ float reg_at(const float* r0, const float* r1, const float* r2,
                                        int b, int ch, int lvl, int p) {
  if (lvl == 0) return r0[((size_t)(b * NREG + ch)) * A0 + p];
  if (lvl == 1) return r1[((size_t)(b * NREG + ch)) * A1 + p];
  return r2[((size_t)(b * NREG + ch)) * A2 + p];
}

__device__ __forceinline__ void gtbox(const float* boxes, int b, int m,
                                      float& x1, float& y1, float& x2, float& y2, bool& valid) {
  const float* q = boxes + ((size_t)(b * NM + m)) * 4;
  float cx = q[0], cy = q[1], w = q[2], h = q[3];
  x1 = (cx - w * 0.5f) * 640.f; y1 = (cy - h * 0.5f) * 640.f;
  x2 = (cx + w * 0.5f) * 640.f; y2 = (cy + h * 0.5f) * 640.f;
  valid = (x1 + y1 + x2 + y2) > 0.f;
}

__device__ __forceinline__ float ciou_f(float b1x1, float b1y1, float b1x2, float b1y2,
                                        float b2x1, float b2y1, float b2x2, float b2y2) {
  const float eps = 1e-7f;
  float w1 = b1x2 - b1x1, h1 = b1y2 - b1y1;
  float w2 = b2x2 - b2x1, h2 = b2y2 - b2y1;
  float iw = fmaxf(fminf(b1x2, b2x2) - fmaxf(b1x1, b2x1), 0.f);
  float ih = fmaxf(fminf(b1y2, b2y2) - fmaxf(b1y1, b2y1), 0.f);
  float inter = iw * ih;
  float uni = w1 * h1 + w2 * h2 - inter + eps;
  float iou = inter / uni;
  float cw = fmaxf(b1x2, b2x2) - fminf(b1x1, b2x1);
  float ch = fmaxf(b1y2, b2y2) - fminf(b1y1, b2y1);
  float c2 = cw * cw + ch * ch + eps;
  float dx = b2x1 + b2x2 - b1x1 - b1x2;
  float dy = b2y1 + b2y2 - b1y1 - b1y2;
  float rho2 = (dx * dx + dy * dy) * 0.25f;
  float at = atanf(w2 / (h2 + eps)) - atanf(w1 / (h1 + eps));
  float v = 0.4052847345693511f * at * at;   // 4/pi^2
  float alpha = v / (v - iou + (1.0f + eps));
  return iou - (rho2 / c2 + v * alpha);
}

__device__ __forceinline__ float align_of(float sc, float o) {
  float o2 = o * o, o4 = o2 * o2;
  return sqrtf(sc) * (o2 * o4);  // sc^0.5 * o^6
}

__device__ __forceinline__ float softplus_fast(float x) {
  float e = __expf(-fabsf(x));
  return fmaxf(x, 0.f) + __logf(1.f + e);
}

// ---------- kernel 1: zero scratch + LDS-transpose decode (float4 staging) ----------

__global__ __launch_bounds__(256) void k_dec(
    const float* r0, const float* r1, const float* r2,
    float4* bb4, float4* mls4, int* fgcnt, int* msum,
    unsigned* pos_am, unsigned* pos_ov, double* gt_acc, int* done_ctr) {
  __shared__ __align__(16) float lds[32 * 256];
  const int tid = threadIdx.x;
  const int g = blockIdx.x * 256 + tid;
  if (g < NB * NA) { fgcnt[g] = 0; msum[g] = 0; }
  if (g < NB * NM) { pos_am[g] = 0u; pos_ov[g] = 0u; }
  if (g < NB * NM * 4) gt_acc[g] = 0.0;
  if (g == 0) *done_ctr = 0;

  const int d = blockIdx.x;
  const int b = d / TILES_PER_B, u = d % TILES_PER_B;
  int lvl, tile;
  if (u < 25)      { lvl = 0; tile = u; }
  else if (u < 32) { lvl = 1; tile = u - 25; }
  else             { lvl = 2; tile = u - 32; }
  const int HW   = (lvl == 0) ? A0 : (lvl == 1 ? A1 : A2);
  const int W    = (lvl == 0) ? 80 : (lvl == 1 ? 40 : 20);
  const int loff = (lvl == 0) ? 0  : (lvl == 1 ? A0 : A0 + A1);
  const float* rg = (lvl == 0) ? r0 : (lvl == 1 ? r1 : r2);
  const int base_p = tile * 256;
  const int valid  = min(256, HW - base_p);
  const float* src = rg + (size_t)b * NREG * HW + base_p;

  const int g4 = tid >> 6;   // row-within-group-of-4
  const int l4 = tid & 63;   // float4 column index

  float dist[4], mlv[4];
#pragma unroll
  for (int ph = 0; ph < 2; ++ph) {
    if (l4 * 4 < valid) {
#pragma unroll
      for (int c4 = 0; c4 < 8; ++c4) {
        int ch = c4 * 4 + g4;
        float4 v = *(const float4*)(src + (size_t)(ph * 32 + ch) * HW + l4 * 4);
        *(float4*)&lds[ch * 256 + l4 * 4] = v;
      }
    }
    __syncthreads();
    if (tid < valid) {
#pragma unroll
      for (int sh = 0; sh < 2; ++sh) {
        const float* col = &lds[(sh * 16) * 256 + tid];
        float mx = col[0];
#pragma unroll
        for (int r = 1; r < 16; ++r) mx = fmaxf(mx, col[r * 256]);
        float se = 0.f, ws = 0.f;
#pragma unroll
        for (int r = 0; r < 16; ++r) {
          float e = __expf(col[r * 256] - mx);
          se += e; ws += e * (float)r;
        }
        dist[ph * 2 + sh] = ws / se;
        mlv[ph * 2 + sh]  = mx + __logf(se);
      }
    }
    __syncthreads();
  }
  if (tid < valid) {
    int p = base_p + tid;
    float ax = (float)(p % W), ay = (float)(p / W);
    int t = b * NA + loff + p;
    bb4[t]  = make_float4(ax - dist[0], ay - dist[1], ax + dist[2], ay + dist[3]);
    mls4[t] = make_float4(mlv[0], mlv[1], mlv[2], mlv[3]);
  }
}

// ---------- kernel 2: assign (blocks < ASN_BLKS) ∥ BCE (rest) ----------

__global__ __launch_bounds__(256) void k_mid(
    const float* boxes, const int* labels, const float4* bb,
    const float* c0, const float* c1, const float* c2,
    int* fgcnt, int* msum, double* bce_part) {
  __shared__ float sv[CAP];
  __shared__ int   si[CAP];
  __shared__ int   s_n;
  __shared__ double sred[256];
  const int tid = threadIdx.x;

  if (blockIdx.x >= ASN_BLKS) {
    // ---- BCE softplus partials ----
    const int bce_blk = blockIdx.x - ASN_BLKS;
    const size_t N0 = (size_t)NB * NCC * A0 / 4;
    const size_t N1 = (size_t)NB * NCC * A1 / 4;
    const size_t N2 = (size_t)NB * NCC * A2 / 4;
    const size_t NT = N0 + N1 + N2;
    const float4* f0 = (const float4*)c0;
    const float4* f1 = (const float4*)c1;
    const float4* f2 = (const float4*)c2;
    const size_t i0 = (size_t)bce_blk * 256 + tid;
    const size_t stride = (size_t)BCE_BLKS * 256;
    float s0 = 0.f, s1 = 0.f;
    for (size_t i = i0; i < NT; i += stride) {
      float4 v;
      if (i < N0) v = f0[i];
      else if (i < N0 + N1) v = f1[i - N0];
      else v = f2[i - N0 - N1];
      s0 += softplus_fast(v.x) + softplus_fast(v.z);
      s1 += softplus_fast(v.y) + softplus_fast(v.w);
    }
    sred[tid] = (double)(s0 + s1);
    __syncthreads();
    for (int off = 128; off; off >>= 1) {
      if (tid < off) sred[tid] += sred[tid + off];
      __syncthreads();
    }
    if (tid == 0) bce_part[bce_blk] = sred[0];
    return;
  }

  // ---- assignment: rect-scan candidates + wave-register top-10 ----
  const int bm = blockIdx.x;
  const int b = bm / NM, m = bm % NM;
  const int lane = tid & 63;

  float gx1, gy1, gx2, gy2; bool valid;
  gtbox(boxes, b, m, gx1, gy1, gx2, gy2, valid);
  if (!valid) return;   // uniform per block
  int lbl = labels[bm]; if (lbl < 0) lbl = 0; if (lbl >= NCC) lbl = NCC - 1;
  if (tid == 0) s_n = 0;
  __syncthreads();

  const int   Ws[3]   = {80, 40, 20};
  const float ss[3]   = {8.f, 16.f, 32.f};
  const int   loff[3] = {0, A0, A0 + A1};
  int rx0[3], ry0[3], rw[3], bc[3];
  int total = 0;
  for (int l = 0; l < 3; ++l) {
    float s = ss[l]; int W = Ws[l];
    int ax0 = (int)floorf((gx1 + 1e-9f) / s);
    int ax1 = (int)ceilf((gx2 - 1e-9f) / s);
    int ay0 = (int)floorf((gy1 + 1e-9f) / s);
    int ay1 = (int)ceilf((gy2 - 1e-9f) / s);
    ax0 = max(ax0, 0); ay0 = max(ay0, 0);
    ax1 = min(ax1, W - 1); ay1 = min(ay1, W - 1);
    rx0[l] = ax0; ry0[l] = ay0;
    rw[l] = max(0, ax1 - ax0 + 1);
    int rhl = max(0, ay1 - ay0 + 1);
    bc[l] = total;
    total += rw[l] * rhl;
  }
  int iters = (total + 255) >> 8;
  for (int it = 0; it < iters; ++it) {
    int idx = it * 256 + tid;
    bool pred = false; float am = 0.f; int a = 0;
    if (idx < total) {
      int l = (idx >= bc[2]) ? 2 : ((idx >= bc[1]) ? 1 : 0);
      int r = idx - bc[l];
      int iy = r / rw[l], ix = r - iy * rw[l];
      int axg = rx0[l] + ix, ayg = ry0[l] + iy;
      a = loff[l] + ayg * Ws[l] + axg;
      float s = ss[l];
      float axp = (float)axg * s, ayp = (float)ayg * s;
      float mn = fminf(fminf(axp - gx1, ayp - gy1), fminf(gx2 - axp, gy2 - ayp));
      if (mn > 1e-9f) {
        pred = true;
        float4 pb = bb[(size_t)b * NA + a];
        float c = ciou_f(gx1, gy1, gx2, gy2, pb.x * s, pb.y * s, pb.z * s, pb.w * s);
        float o = fmaxf(c, 0.f);
        float x = cls_at(c0, c1, c2, b, lbl, a);
        float sc = 1.f / (1.f + expf(-x));
        am = align_of(sc, o);
      }
    }
    unsigned long long mask = __ballot(pred);
    if (mask) {
      int nact = __popcll(mask);
      int leader = __ffsll(mask) - 1;
      int basec = 0;
      if (lane == leader) basec = atomicAdd(&s_n, nact);
      basec = __shfl(basec, leader);
      if (pred) {
        int off = basec + __popcll(mask & ((1ull << lane) - 1ull));
        if (off < CAP) { sv[off] = am; si[off] = a; }
      }
    }
  }
  __syncthreads();
  int n = s_n; if (n > CAP) n = CAP;
  if (n == 0) return;
  if (tid >= 64) return;           // selection: wave 0 only, wave-synchronous

  float v[12]; int ix[12];
#pragma unroll
  for (int k = 0; k < 12; ++k) {
    int j = k * 64 + tid;
    bool in = (j < n);
    v[k]  = in ? sv[j] : -2.f;
    ix[k] = in ? si[j] : (1 << 30);
  }
  int cnt = 0;
#pragma unroll
  for (int k = 0; k < 12; ++k) cnt += (v[k] > 0.f) ? 1 : 0;
  for (int o = 32; o; o >>= 1) cnt += __shfl_xor(cnt, o);
  int npos = cnt;

  if (npos > 10) {
    for (int p = 0; p < 10; ++p) {
      float bv = -1.f; int bi = 1 << 30;
#pragma unroll
      for (int k = 0; k < 12; ++k) {
        if (v[k] > bv || (v[k] == bv && ix[k] < bi)) { bv = v[k]; bi = ix[k]; }
      }
      for (int o = 32; o; o >>= 1) {
        float wv = __shfl_xor(bv, o); int wi = __shfl_xor(bi, o);
        if (wv > bv || (wv == bv && wi < bi)) { bv = wv; bi = wi; }
      }
#pragma unroll
      for (int k = 0; k < 12; ++k) if (ix[k] == bi) v[k] = -1.f;
      if (tid == 0) {
        atomicAdd(&fgcnt[(size_t)b * NA + bi], 1);   // fire-and-forget
        atomicAdd(&msum[(size_t)b * NA + bi], m);
      }
    }
  } else {
#pragma unroll
    for (int k = 0; k < 12; ++k) {
      if (v[k] > 0.f) {
        atomicAdd(&fgcnt[(size_t)b * NA + ix[k]], 1);
        atomicAdd(&msum[(size_t)b * NA + ix[k]], m);
      }
    }
    // zero-tie fill (anchor index < 10 — rare corner); sv/si in LDS unmodified
    int need = 10 - npos;
    for (int j = tid; j < n; j += 64) {
      if (sv[j] == 0.f) {
        int i = si[j];
        if (i < 10) {
          int pb = 0;
          for (int q = 0; q < n; ++q) pb += (sv[q] > 0.f && si[q] < i) ? 1 : 0;
          if (i - pb < need) {
            atomicAdd(&fgcnt[(size_t)b * NA + i], 1);
            atomicAdd(&msum[(size_t)b * NA + i], m);
          }
        }
      }
    }
  }
}

// ---------- kernel 3: resolve + per-gt buckets + last-block final compose ----------
// gt_acc[g*4+q]: q0=Σam q1=Σam·x q2=Σam·(1-iou) q3=Σam·dfl

__global__ __launch_bounds__(256) void k_rpf(
    const float* boxes, const int* labels,
    const float4* bb, const float4* mls,
    const float* c0, const float* c1, const float* c2,
    const float* r0, const float* r1, const float* r2,
    const int* fgcnt, const int* msum,
    unsigned* pos_am, unsigned* pos_ov, double* gt_acc,
    int* done_ctr, const double* bce_part, float* out) {
  const int tid = threadIdx.x;
  const int t = blockIdx.x * 256 + tid;   // grid covers NB*NA exactly
  int fg = fgcnt[t];
  if (fg > 0) {
    int b = t / NA, a = t % NA;
    float ax, ay, s; int lvl, p;
    anch(a, ax, ay, s, lvl, p);
    float axp = ax * s, ayp = ay * s;
    float4 pb = bb[t];
    float px1 = pb.x * s, py1 = pb.y * s, px2 = pb.z * s, py2 = pb.w * s;
    int asn; float o;
    if (fg == 1) {
      asn = msum[t];
      float gx1, gy1, gx2, gy2; bool valid;
      gtbox(boxes, b, asn, gx1, gy1, gx2, gy2, valid);
      o = fmaxf(ciou_f(gx1, gy1, gx2, gy2, px1, py1, px2, py2), 0.f);
    } else {
      float bv = -1e30f; int bi = 0;
      for (int m = 0; m < NM; ++m) {
        float gx1, gy1, gx2, gy2; bool valid;
        gtbox(boxes, b, m, gx1, gy1, gx2, gy2, valid);
        float om = 0.f;
        if (valid) {
          float mn = fminf(fminf(axp - gx1, ayp - gy1), fminf(gx2 - axp, gy2 - ayp));
          if (mn > 1e-9f)
            om = fmaxf(ciou_f(gx1, gy1, gx2, gy2, px1, py1, px2, py2), 0.f);
        }
        if (om > bv) { bv = om; bi = m; }
      }
      asn = bi; o = bv;
    }
    if (o > 0.f) {
      int g = b * NM + asn;
      int lbl = labels[g]; if (lbl < 0) lbl = 0; if (lbl >= NCC) lbl = NCC - 1;
      float x = cls_at(c0, c1, c2, b, lbl, a);
      float sc = 1.f / (1.f + expf(-x));
      float am = align_of(sc, o);
      atomicMax(&pos_am[g], __float_as_uint(am));
      atomicMax(&pos_ov[g], __float_as_uint(o));
      if (am > 0.f) {
        float gx1, gy1, gx2, gy2; bool valid;
        gtbox(boxes, b, asn, gx1, gy1, gx2, gy2, valid);
        float inv_s = 1.f / s;
        float tx1 = gx1 * inv_s, ty1 = gy1 * inv_s, tx2 = gx2 * inv_s, ty2 = gy2 * inv_s;
        float iou = ciou_f(pb.x, pb.y, pb.z, pb.w, tx1, ty1, tx2, ty2);
        float4 ml = mls[t];
        float tgt[4] = { ax - tx1, ay - ty1, tx2 - ax, ty2 - ay };
        float mlv[4] = { ml.x, ml.y, ml.z, ml.w };
        float dfl = 0.f;
        for (int sd = 0; sd < 4; ++sd) {
          float tv = fminf(fmaxf(tgt[sd], 0.f), 14.99f);
          float tlf = floorf(tv);
          int tl = (int)tlf;
          float wl = (tlf + 1.f) - tv;
          float xtl = reg_at(r0, r1, r2, b, sd * 16 + tl,     lvl, p);
          float xtr = reg_at(r0, r1, r2, b, sd * 16 + tl + 1, lvl, p);
          dfl += -((xtl - mlv[sd]) * wl + (xtr - mlv[sd]) * (1.f - wl));
        }
        dfl *= 0.25f;
        atomicAdd(&gt_acc[g * 4 + 0], (double)am);
        atomicAdd(&gt_acc[g * 4 + 1], (double)(am * x));
        atomicAdd(&gt_acc[g * 4 + 2], (double)(am * (1.f - iou)));
        atomicAdd(&gt_acc[g * 4 + 3], (double)(am * dfl));
      }
    }
  }

  // ---- last-block-done epilogue (atomics are per-address coherent; no fence) ----
  __shared__ int s_last;
  __syncthreads();
  if (tid == 0) {
    int old = atomicAdd(done_ctr, 1);
    s_last = (old == (int)gridDim.x - 1) ? 1 : 0;
  }
  __syncthreads();
  if (!s_last) return;

  double tss = 0.0, sx = 0.0, siou = 0.0, sdfl = 0.0, bce = 0.0;
  for (int g = tid; g < NB * NM; g += 256) {
    float pam = __uint_as_float(atomicAdd(&pos_am[g], 0u));
    float pov = __uint_as_float(atomicAdd(&pos_ov[g], 0u));
    double sc = (double)pov / ((double)pam + 1e-9);
    tss  += atomicAdd(&gt_acc[g * 4 + 0], 0.0) * sc;
    sx   += atomicAdd(&gt_acc[g * 4 + 1], 0.0) * sc;
    siou += atomicAdd(&gt_acc[g * 4 + 2], 0.0) * sc;
    sdfl += atomicAdd(&gt_acc[g * 4 + 3], 0.0) * sc;
  }
  for (int i = tid; i < BCE_BLKS; i += 256) bce += bce_part[i];  // prior dispatch: visible
  __shared__ double sred[256];
  double vals[5] = { tss, sx, siou, sdfl, bce };
  double tot[5];
  for (int q = 0; q < 5; ++q) {
    sred[tid] = vals[q];
    __syncthreads();
    for (int off = 128; off; off >>= 1) {
      if (tid < off) sred[tid] += sred[tid + off];
      __syncthreads();
    }
    tot[q] = sred[0];
    __syncthreads();
  }
  if (tid == 0) {
    double t5 = tot[0]; if (t5 < 1.0) t5 = 1.0;
    double l0 = 0.5 * (tot[4] - tot[1]) / t5;
    double l1 = 7.5 * tot[2] / t5;
    double l2 = 1.5 * tot[3] / t5;
    out[0] = (float)(l0 + l1 + l2);
    out[1] = (float)l0;
    out[2] = (float)l1;
    out[3] = (float)l2;
  }
}

// ---------- launch ----------

extern "C" void kernel_launch(void* const* d_in, const int* in_sizes, int n_in,
                              void* d_out, int out_size, void* d_ws, size_t ws_size,
                              hipStream_t stream) {
  (void)in_sizes; (void)n_in; (void)out_size; (void)ws_size;
  const float* cls0  = (const float*)d_in[0];
  const float* cls1  = (const float*)d_in[1];
  const float* cls2  = (const float*)d_in[2];
  const float* reg0  = (const float*)d_in[3];
  const float* reg1  = (const float*)d_in[4];
  const float* reg2  = (const float*)d_in[5];
  const float* boxes = (const float*)d_in[6];
  const int*   labels = (const int*)d_in[7];
  float* out = (float*)d_out;

  const size_t BA = (size_t)NB * NA;  // 134400
  const int    BM = NB * NM;          // 512

  char* wsb = (char*)d_ws;
  double*   bce_part = (double*)wsb;                        // BCE_BLKS
  double*   gt_acc   = bce_part + BCE_BLKS;                 // BM*4   (zeroed in k_dec)
  unsigned* pos_am   = (unsigned*)(gt_acc + (size_t)BM * 4);// BM     (zeroed)
  unsigned* pos_ov   = pos_am + BM;                         // BM     (zeroed)
  int*      done_ctr = (int*)(pos_ov + BM);                 // 1 (+pad, zeroed)
  int*      fgcnt    = done_ctr + 4;                        // BA     (zeroed)
  int*      msum     = fgcnt + BA;                          // BA     (zeroed)
  float*    bbp      = (float*)(msum + BA);                 // BA*4
  float*    mlsp     = bbp + BA * 4;                        // BA*4

  float4* bb  = (float4*)bbp;
  float4* mls = (float4*)mlsp;

  k_dec<<<DEC_BLKS, 256, 0, stream>>>(reg0, reg1, reg2, bb, mls,
                                      fgcnt, msum, pos_am, pos_ov, gt_acc, done_ctr);
  k_mid<<<MID_GRID, 256, 0, stream>>>(boxes, labels, (const float4*)bb,
                                      cls0, cls1, cls2, fgcnt, msum, bce_part);
  k_rpf<<<PL_GRID, 256, 0, stream>>>(boxes, labels, (const float4*)bb, (const float4*)mls,
                                     cls0, cls1, cls2, reg0, reg1, reg2,
                                     fgcnt, msum, pos_am, pos_ov, gt_acc,
                                     done_ctr, bce_part, out);
}